// Round 6
// baseline (254.430 us; speedup 1.0000x reference)
//
#include <hip/hip_runtime.h>
#include <hip/hip_bf16.h>

namespace {
constexpr int kB = 8;
constexpr int kC = 64;
constexpr int kH = 48;
constexpr int kW = 48;
constexpr int kS = kH * kW;          // 2304
constexpr float kEps = 1.1920929e-07f;
}

typedef __attribute__((ext_vector_type(8))) short short8;   // 8 bf16 (4 VGPR)
typedef __attribute__((ext_vector_type(4))) float f32x4;

// fp32 -> bf16 (round-nearest-even), bit-level
__device__ __forceinline__ short f2bf(float x) {
  unsigned u = __float_as_uint(x);
  u += 0x7fffu + ((u >> 16) & 1u);
  return (short)(u >> 16);
}
__device__ __forceinline__ float bf2f(short s) {
  return __uint_as_float(((unsigned)(unsigned short)s) << 16);
}

// ---------------------------------------------------------------------------
// F1: fused prep.
//  blocks [0,576):    transpose q,k [b][c][s] fp32 -> [b][s][c] bf16
//  blocks [576,1728): v fp32 -> bf16 cast (same layout), 1024 elems/block
//  blocks [1728,1904): weight prep (wq,wk bf16; conv_w -> [tap][co][ci] bf16)
// ---------------------------------------------------------------------------
__global__ __launch_bounds__(256) void fused_prep(
    const float* __restrict__ q, const float* __restrict__ k,
    const float* __restrict__ v, const float* __restrict__ wq,
    const float* __restrict__ wk, const float* __restrict__ conv_w,
    short* __restrict__ qt, short* __restrict__ kt, short* __restrict__ vt,
    short* __restrict__ wqb, short* __restrict__ wkb, short* __restrict__ wt2) {
  const int blk = blockIdx.x;
  if (blk < 576) {
    __shared__ float tile[64][65];
    const int zz = blk / 36;         // b*2 + which
    const int bx = blk % 36;
    const int b = zz >> 1;
    const float* src = (zz & 1) ? k : q;
    short* dst = (zz & 1) ? kt : qt;
    const int s0 = bx * 64;
    const int tx = threadIdx.x & 63;
    const int ty = threadIdx.x >> 6;
#pragma unroll
    for (int r = 0; r < 16; ++r) {
      int c = r * 4 + ty;
      tile[c][tx] = src[((size_t)b * kC + c) * kS + s0 + tx];
    }
    __syncthreads();
#pragma unroll
    for (int r = 0; r < 16; ++r) {
      int s = r * 4 + ty;
      dst[((size_t)b * kS + s0 + s) * kC + tx] = f2bf(tile[tx][s]);
    }
  } else if (blk < 1728) {
    int idx = ((blk - 576) * 256 + threadIdx.x) * 4;
    float4 x = *reinterpret_cast<const float4*>(v + idx);
    int2 o;
    o.x = ((int)(unsigned short)f2bf(x.y) << 16) | (unsigned short)f2bf(x.x);
    o.y = ((int)(unsigned short)f2bf(x.w) << 16) | (unsigned short)f2bf(x.z);
    *reinterpret_cast<int2*>(vt + idx) = o;
  } else {
    int idx = (blk - 1728) * 256 + threadIdx.x;
    if (idx < 4096) {
      wqb[idx] = f2bf(wq[idx]);
    } else if (idx < 8192) {
      wkb[idx - 4096] = f2bf(wk[idx - 4096]);
    } else {
      int i = idx - 8192;
      int ci = i & 63, co = (i >> 6) & 63, tap = i >> 12;
      wt2[i] = f2bf(conv_w[co * 576 + ci * 9 + tap]);
    }
  }
}

// ---------------------------------------------------------------------------
// F2: fused q/k projection GEMMs.
//  blocks [0,288):   q path (conv 9-tap GEMM + RMSNorm + wq proj, *0.25)
//  blocks [288,576): k path (RMSNorm + wk proj)
// ---------------------------------------------------------------------------
__global__ __launch_bounds__(256) void fused_qk_gemm(
    const short* __restrict__ qt, const short* __restrict__ kt,
    const short* __restrict__ wt2, const short* __restrict__ wqb,
    const short* __restrict__ wkb,
    const float* __restrict__ nq_w, const float* __restrict__ nk_w,
    const float* __restrict__ bq, const float* __restrict__ bk,
    short* __restrict__ qp, short* __restrict__ kp) {
  __shared__ __align__(16) short ln[4][16][80];
  const int blk = blockIdx.x;
  const int t = threadIdx.x;
  const int ws = t >> 6;
  const int L = t & 63;
  const int quad = L >> 4;
  const int l16 = L & 15;
  const short8 zero8 = {0, 0, 0, 0, 0, 0, 0, 0};

  if (blk < 288) {
    // ---- q path ----
    const int b = blk / 36;
    const int sBase = (blk % 36) * 64 + ws * 16;
    const int s = sBase + l16;
    const int h = s / kW, w = s % kW;

    f32x4 acc[4] = {{0.f, 0.f, 0.f, 0.f}, {0.f, 0.f, 0.f, 0.f},
                    {0.f, 0.f, 0.f, 0.f}, {0.f, 0.f, 0.f, 0.f}};
#pragma unroll
    for (int tap = 0; tap < 9; ++tap) {
      const int dh = tap / 3 - 1, dw = tap % 3 - 1;
      const bool valid = (unsigned)(h + dh) < (unsigned)kH &&
                         (unsigned)(w + dw) < (unsigned)kW;
      const int srow = valid ? (s + dh * kW + dw) : s;
      const short8* ap = reinterpret_cast<const short8*>(
          qt + ((size_t)b * kS + srow) * kC);
#pragma unroll
      for (int kh = 0; kh < 2; ++kh) {
        short8 af = ap[kh * 4 + quad];
        af = valid ? af : zero8;
        const short* wb = wt2 + tap * 4096 + l16 * kC + kh * 32 + quad * 8;
#pragma unroll
        for (int nt = 0; nt < 4; ++nt) {
          short8 bf = *reinterpret_cast<const short8*>(wb + nt * 16 * kC);
          acc[nt] = __builtin_amdgcn_mfma_f32_16x16x32_bf16(af, bf, acc[nt], 0, 0, 0);
        }
      }
    }
    float rstd[4];
#pragma unroll
    for (int reg = 0; reg < 4; ++reg) {
      float pr = acc[0][reg] * acc[0][reg] + acc[1][reg] * acc[1][reg]
               + acc[2][reg] * acc[2][reg] + acc[3][reg] * acc[3][reg];
      pr += __shfl_xor(pr, 1, 64);
      pr += __shfl_xor(pr, 2, 64);
      pr += __shfl_xor(pr, 4, 64);
      pr += __shfl_xor(pr, 8, 64);
      rstd[reg] = rsqrtf(pr * (1.0f / kC) + kEps);
    }
#pragma unroll
    for (int nt = 0; nt < 4; ++nt) {
      float g = nq_w[nt * 16 + l16];
#pragma unroll
      for (int reg = 0; reg < 4; ++reg) {
        ln[ws][quad * 4 + reg][nt * 16 + l16] = f2bf(acc[nt][reg] * rstd[reg] * g);
      }
    }
    __syncthreads();
    f32x4 acc2[4] = {{0.f, 0.f, 0.f, 0.f}, {0.f, 0.f, 0.f, 0.f},
                     {0.f, 0.f, 0.f, 0.f}, {0.f, 0.f, 0.f, 0.f}};
#pragma unroll
    for (int kh = 0; kh < 2; ++kh) {
      short8 af = *reinterpret_cast<const short8*>(&ln[ws][l16][kh * 32 + quad * 8]);
#pragma unroll
      for (int nt = 0; nt < 4; ++nt) {
        short8 bf = *reinterpret_cast<const short8*>(
            wqb + (nt * 16 + l16) * kC + kh * 32 + quad * 8);
        acc2[nt] = __builtin_amdgcn_mfma_f32_16x16x32_bf16(af, bf, acc2[nt], 0, 0, 0);
      }
    }
#pragma unroll
    for (int nt = 0; nt < 4; ++nt) {
      const int e = nt * 16 + l16;
      float bias = bq[e];
#pragma unroll
      for (int reg = 0; reg < 4; ++reg) {
        qp[((size_t)b * kS + sBase + quad * 4 + reg) * kC + e] =
            f2bf((acc2[nt][reg] + bias) * 0.25f);
      }
    }
  } else {
    // ---- k path ----
    const int idx = blk - 288;
    const int b = idx / 36;
    const int sBase = (idx % 36) * 64 + ws * 16;
    const int s = sBase + l16;

    const short8* ap = reinterpret_cast<const short8*>(
        kt + ((size_t)b * kS + s) * kC);
    short8 af0 = ap[quad];
    short8 af1 = ap[4 + quad];

    float xs[16];
#pragma unroll
    for (int j = 0; j < 8; ++j) { xs[j] = bf2f(af0[j]); xs[8 + j] = bf2f(af1[j]); }
    float sum = 0.f;
#pragma unroll
    for (int j = 0; j < 16; ++j) sum = fmaf(xs[j], xs[j], sum);
    sum += __shfl_xor(sum, 16, 64);
    sum += __shfl_xor(sum, 32, 64);
    float rstd = rsqrtf(sum * (1.0f / kC) + kEps);

    const float* n0 = nk_w + quad * 8;
#pragma unroll
    for (int j = 0; j < 8; ++j) {
      af0[j] = f2bf(xs[j] * rstd * n0[j]);
      af1[j] = f2bf(xs[8 + j] * rstd * n0[32 + j]);
    }

    f32x4 acc[4] = {{0.f, 0.f, 0.f, 0.f}, {0.f, 0.f, 0.f, 0.f},
                    {0.f, 0.f, 0.f, 0.f}, {0.f, 0.f, 0.f, 0.f}};
#pragma unroll
    for (int nt = 0; nt < 4; ++nt) {
      short8 bf0 = *reinterpret_cast<const short8*>(
          wkb + (nt * 16 + l16) * kC + quad * 8);
      short8 bf1 = *reinterpret_cast<const short8*>(
          wkb + (nt * 16 + l16) * kC + 32 + quad * 8);
      acc[nt] = __builtin_amdgcn_mfma_f32_16x16x32_bf16(af0, bf0, acc[nt], 0, 0, 0);
      acc[nt] = __builtin_amdgcn_mfma_f32_16x16x32_bf16(af1, bf1, acc[nt], 0, 0, 0);
    }
#pragma unroll
    for (int nt = 0; nt < 4; ++nt) {
      const int e = nt * 16 + l16;
      float bias = bk[e];
#pragma unroll
      for (int reg = 0; reg < 4; ++reg) {
        kp[((size_t)b * kS + sBase + quad * 4 + reg) * kC + e] =
            f2bf(acc[nt][reg] + bias);
      }
    }
  }
}

// ---------------------------------------------------------------------------
// K3: MFMA attention, round-6 structure.
//  - Q masked per head ONCE per block (A/B per-lane layouts coincide for 16x16)
//  - max-free softmax: pass1 accumulates l_h = sum_j e^{s}; pass2 computes
//    w(i,j) = sum_h e^{s_h} * (0.25/l_h) directly.
//  - wtile double-buffered: one barrier per j-tile.
// grid (144, 8), 256 threads (4 waves, each owns a 16-j subtile / dv-tile).
// ---------------------------------------------------------------------------
__global__ __launch_bounds__(256) void attn_mfma(
    const short* __restrict__ qp, const short* __restrict__ kp,
    const short* __restrict__ vt, float* __restrict__ out) {
  __shared__ float pl[4][16][4];      // per-wave l partials [ws][i][h]
  __shared__ float Li[16][4];         // 0.25 / l
  __shared__ __align__(16) short wtile[2][16][72];

  const int b = blockIdx.y;
  const int i0 = blockIdx.x * 16;
  const int t = threadIdx.x;
  const int ws = t >> 6;
  const int L = t & 63;
  const int quad = L >> 4;
  const int l16 = L & 15;

  const short8 zero8 = {0, 0, 0, 0, 0, 0, 0, 0};
  const f32x4 zc = {0.f, 0.f, 0.f, 0.f};

  // Q fragments for row i = i0+l16, masked per head (loop-invariant).
  const short8* qrow = reinterpret_cast<const short8*>(
      qp + ((size_t)b * kS + i0 + l16) * kC);
  const short8 qf0 = qrow[quad];
  const short8 qf1 = qrow[4 + quad];
  const bool lo = quad < 2;
  const short8 qm0 = lo ? qf0 : zero8;   // head0: k 0..15 of window 0
  const short8 qm1 = lo ? zero8 : qf0;   // head1: k 16..31 of window 0
  const short8 qm2 = lo ? qf1 : zero8;   // head2
  const short8 qm3 = lo ? zero8 : qf1;   // head3

  const short* kbase = kp + ((size_t)b * kS + ws * 16 + l16) * kC;

  // ---- pass 1: l_h = sum_j e^{s_h}  (no barriers in loop) ----
  float l0 = 0.f, l1 = 0.f, l2 = 0.f, l3 = 0.f;
  for (int jt = 0; jt < kS / 64; ++jt) {
    const short8* krow = reinterpret_cast<const short8*>(kbase + jt * 64 * kC);
    const short8 kf0 = krow[quad];
    const short8 kf1 = krow[4 + quad];
    // A=K (rows j), B=masked Q (cols i) -> lane: rows j=quad*4+reg, col i=l16
    f32x4 s0 = __builtin_amdgcn_mfma_f32_16x16x32_bf16(kf0, qm0, zc, 0, 0, 0);
    f32x4 s1 = __builtin_amdgcn_mfma_f32_16x16x32_bf16(kf0, qm1, zc, 0, 0, 0);
    f32x4 s2 = __builtin_amdgcn_mfma_f32_16x16x32_bf16(kf1, qm2, zc, 0, 0, 0);
    f32x4 s3 = __builtin_amdgcn_mfma_f32_16x16x32_bf16(kf1, qm3, zc, 0, 0, 0);
    l0 += (__expf(s0[0]) + __expf(s0[1])) + (__expf(s0[2]) + __expf(s0[3]));
    l1 += (__expf(s1[0]) + __expf(s1[1])) + (__expf(s1[2]) + __expf(s1[3]));
    l2 += (__expf(s2[0]) + __expf(s2[1])) + (__expf(s2[2]) + __expf(s2[3]));
    l3 += (__expf(s3[0]) + __expf(s3[1])) + (__expf(s3[2]) + __expf(s3[3]));
  }
  // reduce over quads (lanes differing in bits 4,5)
  l0 += __shfl_xor(l0, 16, 64); l0 += __shfl_xor(l0, 32, 64);
  l1 += __shfl_xor(l1, 16, 64); l1 += __shfl_xor(l1, 32, 64);
  l2 += __shfl_xor(l2, 16, 64); l2 += __shfl_xor(l2, 32, 64);
  l3 += __shfl_xor(l3, 16, 64); l3 += __shfl_xor(l3, 32, 64);
  if (quad == 0) {
    pl[ws][l16][0] = l0; pl[ws][l16][1] = l1;
    pl[ws][l16][2] = l2; pl[ws][l16][3] = l3;
  }
  __syncthreads();
  if (t < 64) {
    const int i = t >> 2, h = t & 3;
    Li[i][h] = 0.25f / (pl[0][i][h] + pl[1][i][h] + pl[2][i][h] + pl[3][i][h]);
  }
  __syncthreads();

  float c[4][4];   // [reg][h] for rows i = quad*4+reg
#pragma unroll
  for (int reg = 0; reg < 4; ++reg)
#pragma unroll
    for (int h = 0; h < 4; ++h) c[reg][h] = Li[quad * 4 + reg][h];

  // ---- pass 2: weights + PV ----
  f32x4 Oacc = {0.f, 0.f, 0.f, 0.f};
  const short* vbase = vt + ((size_t)b * kC + ws * 16 + l16) * kS + quad * 8;

  for (int jt = 0; jt < kS / 64; ++jt) {
    const short8* krow = reinterpret_cast<const short8*>(kbase + jt * 64 * kC);
    const short8 kf0 = krow[quad];
    const short8 kf1 = krow[4 + quad];
    // A=masked Q (rows i), B=K (cols j) -> lane: rows i=quad*4+reg, col j=l16
    f32x4 s0 = __builtin_amdgcn_mfma_f32_16x16x32_bf16(qm0, kf0, zc, 0, 0, 0);
    f32x4 s1 = __builtin_amdgcn_mfma_f32_16x16x32_bf16(qm1, kf0, zc, 0, 0, 0);
    f32x4 s2 = __builtin_amdgcn_mfma_f32_16x16x32_bf16(qm2, kf1, zc, 0, 0, 0);
    f32x4 s3 = __builtin_amdgcn_mfma_f32_16x16x32_bf16(qm3, kf1, zc, 0, 0, 0);
    const int buf = jt & 1;
#pragma unroll
    for (int reg = 0; reg < 4; ++reg) {
      float wsum = __expf(s0[reg]) * c[reg][0] + __expf(s1[reg]) * c[reg][1]
                 + __expf(s2[reg]) * c[reg][2] + __expf(s3[reg]) * c[reg][3];
      wtile[buf][quad * 4 + reg][ws * 16 + l16] = f2bf(wsum);
    }
    __syncthreads();
    short8 pf0 = *reinterpret_cast<const short8*>(&wtile[buf][l16][quad * 8]);
    short8 pf1 = *reinterpret_cast<const short8*>(&wtile[buf][l16][32 + quad * 8]);
    short8 vf0 = *reinterpret_cast<const short8*>(vbase + jt * 64);
    short8 vf1 = *reinterpret_cast<const short8*>(vbase + jt * 64 + 32);
    Oacc = __builtin_amdgcn_mfma_f32_16x16x32_bf16(pf0, vf0, Oacc, 0, 0, 0);
    Oacc = __builtin_amdgcn_mfma_f32_16x16x32_bf16(pf1, vf1, Oacc, 0, 0, 0);
  }

#pragma unroll
  for (int reg = 0; reg < 4; ++reg) {
    out[((size_t)b * kS + i0 + quad * 4 + reg) * kC + ws * 16 + l16] = Oacc[reg];
  }
}

// ---------------------------------------------------------------------------
extern "C" void kernel_launch(void* const* d_in, const int* in_sizes, int n_in,
                              void* d_out, int out_size, void* d_ws, size_t ws_size,
                              hipStream_t stream) {
  const float* q      = (const float*)d_in[0];
  const float* k      = (const float*)d_in[1];
  const float* v      = (const float*)d_in[2];
  const float* conv_w = (const float*)d_in[3];
  const float* nq_w   = (const float*)d_in[4];
  const float* nk_w   = (const float*)d_in[5];
  const float* wq     = (const float*)d_in[6];
  const float* bq     = (const float*)d_in[7];
  const float* wk     = (const float*)d_in[8];
  const float* bk     = (const float*)d_in[9];
  float* out = (float*)d_out;

  const size_t N = (size_t)kB * kS * kC;   // 1,179,648
  short* qt  = (short*)d_ws;     // bf16 [b][s][c]
  short* kt  = qt + N;
  short* vt  = kt + N;           // bf16 [b][c][s]
  short* qp  = vt + N;           // bf16 [b][s][64]
  short* kp  = qp + N;
  short* wqb = kp + N;           // bf16 [64][64]
  short* wkb = wqb + 4096;
  short* wt2 = wkb + 4096;       // bf16 [9][64][64]

  fused_prep<<<1904, 256, 0, stream>>>(q, k, v, wq, wk, conv_w,
                                       qt, kt, vt, wqb, wkb, wt2);
  fused_qk_gemm<<<576, 256, 0, stream>>>(qt, kt, wt2, wqb, wkb,
                                         nq_w, nk_w, bq, bk, qp, kp);
  attn_mfma<<<dim3(kS / 16, kB), 256, 0, stream>>>(qp, kp, vt, out);
}